// Round 4
// baseline (4503.350 us; speedup 1.0000x reference)
//
#include <hip/hip_runtime.h>

typedef __attribute__((ext_vector_type(8))) short short8;
typedef __attribute__((ext_vector_type(4))) float floatx4;

#define T_STEPS 256
#define BATCH   64
#define IDIM    1024
#define HDIM    1024
#define KDIM    (IDIM + HDIM)   // fused [X | H] K dimension
#define MB      16              // batch rows per WG
#define HB      16              // hidden cols per WG (per gate)
#define NWG     256             // 4 batch-groups x 64 h-groups
#define NTHR    512             // 8 waves = 8 K-octants (each does all 4 gates)
#define NSUB    8               // arrival sub-counters per batch-group

__device__ __forceinline__ unsigned short f2bf(float f) {
  unsigned u = __float_as_uint(f);
  u += 0x7FFFu + ((u >> 16) & 1u);   // round-to-nearest-even
  return (unsigned short)(u >> 16);
}

// Wcat[g][h][k] bf16, k<1024 -> Wx*mx, k>=1024 -> Wh*mh
__global__ void prep_weights(const float* __restrict__ Wx, const float* __restrict__ Wh,
                             const float* __restrict__ mx, const float* __restrict__ mh,
                             unsigned short* __restrict__ Wcat) {
  int idx = blockIdx.x * blockDim.x + threadIdx.x;
  const int total = 4 * HDIM * KDIM / 4;
  if (idx >= total) return;
  int k4 = idx & (KDIM / 4 - 1);
  int gh = idx >> 9;
  int k = k4 * 4;
  float4 v, m;
  if (k < IDIM) {
    v = *(const float4*)(Wx + (size_t)gh * IDIM + k);
    m = *(const float4*)(mx + (size_t)gh * IDIM + k);
  } else {
    v = *(const float4*)(Wh + (size_t)gh * HDIM + (k - IDIM));
    m = *(const float4*)(mh + (size_t)gh * HDIM + (k - IDIM));
  }
  ushort4 o;
  o.x = f2bf(v.x * m.x); o.y = f2bf(v.y * m.y);
  o.z = f2bf(v.z * m.z); o.w = f2bf(v.w * m.w);
  *(ushort4*)(Wcat + (size_t)gh * KDIM + k) = o;
}

// init H0 (bf16) + zero arrival counters
__global__ void prep_h0(const float* __restrict__ H0, unsigned short* __restrict__ Hbuf0,
                        unsigned* __restrict__ cnt) {
  int i = blockIdx.x * blockDim.x + threadIdx.x;
  if (i < BATCH * HDIM) Hbuf0[i] = f2bf(H0[i]);
  if (i < 4 * NSUB * 16) cnt[i] = 0u;   // 4 bg x 8 sub-counters x 16-dword (64B) lines
}

__global__ void __launch_bounds__(NTHR, 2)
lstm_main(const float* __restrict__ X,            // [T][B][I] f32
          const float* __restrict__ bias,          // [4][H] f32
          const float* __restrict__ C0,            // [B][H] f32
          const unsigned short* __restrict__ Wcat, // [4][H][K] bf16
          unsigned short* __restrict__ Hbuf0,      // [B][H] bf16 double buffer
          unsigned short* __restrict__ Hbuf1,
          unsigned* __restrict__ cnt,              // [4 bg][8 sub] x 16-dword lines
          float* __restrict__ out)                 // [T][B][H] f32
{
  __shared__ float parts[2][4][MB][HB + 1];   // 8704 B, double-buffered, reset-on-read

  const int tid  = threadIdx.x;
  const int wg   = blockIdx.x;
  const int bg   = wg >> 6;
  const int hg   = wg & 63;
  const int b0   = bg * MB;
  const int h0   = hg * HB;

  const int w    = tid >> 6;       // wave = K-octant 0..7 (0-3 = X, 4-7 = H)
  const int lane = tid & 63;
  const int nl   = lane & 15;
  const int quad = lane >> 4;

  // ---- persistent B fragments: Bfr[g][ks] covers k = w*256 + ks*32 + quad*8 .. +8
  short8 Bfr[4][8];
  {
    const short8* wp = (const short8*)Wcat;
#pragma unroll
    for (int g = 0; g < 4; ++g) {
      const int rowbase = (g * HDIM + h0 + nl) * (KDIM / 8);
#pragma unroll
      for (int ks = 0; ks < 8; ++ks)
        Bfr[g][ks] = wp[rowbase + w * 32 + ks * 4 + quad];
    }
  }

  // ---- zero both parts buffers
  for (int i = tid; i < 2 * 4 * MB * (HB + 1); i += NTHR)
    (&parts[0][0][0][0])[i] = 0.f;

  // ---- per-thread cell state (threads 0..255 own a (b,h) cell)
  float c_state = 0.f;
  const int eb = tid >> 4;
  const int eh = tid & 15;
  if (tid < 256) c_state = C0[(b0 + eb) * HDIM + h0 + eh];

  // ---- bias slice (only wave 0 folds it into its accumulator)
  float sb[4];
#pragma unroll
  for (int g = 0; g < 4; ++g) sb[g] = bias[g * HDIM + h0 + nl];

  unsigned* mycnt = cnt + (bg * NSUB + (hg & (NSUB - 1))) * 16;  // this WG's sub-counter
  unsigned* bgcnt = cnt + bg * NSUB * 16;                        // this bg's 8 sub-counters

  __syncthreads();   // parts zero-init visible

  for (int t = 0; t < T_STEPS; ++t) {
    const unsigned short* __restrict__ Hprev = (t & 1) ? Hbuf1 : Hbuf0;
    unsigned short* __restrict__ Hnext       = (t & 1) ? Hbuf0 : Hbuf1;

    floatx4 acc[4];
#pragma unroll
    for (int g = 0; g < 4; ++g) acc[g] = floatx4{0.f, 0.f, 0.f, 0.f};

    if (w < 4) {
      // ---- X octant: plain cached loads, f32->bf16 in-register, never waits
      const uint4* u = (const uint4*)(X + ((size_t)t * BATCH + b0 + nl) * IDIM
                                        + w * 256 + quad * 8);
#pragma unroll
      for (int ks = 0; ks < 8; ++ks) {
        uint4 lo = u[ks * 8];
        uint4 hi = u[ks * 8 + 1];
        short8 af;
        af[0] = (short)f2bf(__uint_as_float(lo.x));
        af[1] = (short)f2bf(__uint_as_float(lo.y));
        af[2] = (short)f2bf(__uint_as_float(lo.z));
        af[3] = (short)f2bf(__uint_as_float(lo.w));
        af[4] = (short)f2bf(__uint_as_float(hi.x));
        af[5] = (short)f2bf(__uint_as_float(hi.y));
        af[6] = (short)f2bf(__uint_as_float(hi.z));
        af[7] = (short)f2bf(__uint_as_float(hi.w));
#pragma unroll
        for (int g = 0; g < 4; ++g)
          acc[g] = __builtin_amdgcn_mfma_f32_16x16x32_bf16(af, Bfr[g][ks], acc[g], 0, 0, 0);
      }
      if (w == 0) {
#pragma unroll
        for (int g = 0; g < 4; ++g)
#pragma unroll
          for (int r = 0; r < 4; ++r)
            acc[g][r] += sb[g];
      }
    } else {
      // ---- H octant: per-wave poll on this bg's arrival counters (proven protocol),
      //      then direct coherent bf16 loads of ONLY this wave's K-quarter
      if (t > 0) {
        const unsigned tgt = 256u * (unsigned)t;   // 4 waves x 64 WGs per step
        for (;;) {
          unsigned s = 0;
#pragma unroll
          for (int k = 0; k < NSUB; ++k)
            s += __hip_atomic_load(bgcnt + k * 16, __ATOMIC_RELAXED, __HIP_MEMORY_SCOPE_AGENT);
          if (s >= tgt) break;
          __builtin_amdgcn_s_sleep(2);
        }
      }
      const unsigned short* hb = Hprev + (size_t)(b0 + nl) * HDIM + (w - 4) * 256 + quad * 8;
      uint4 hq0, hq1, hq2, hq3, hq4, hq5, hq6, hq7;
      asm volatile(
        "global_load_dwordx4 %0, %8, off sc0 sc1\n\t"
        "global_load_dwordx4 %1, %8, off offset:64 sc0 sc1\n\t"
        "global_load_dwordx4 %2, %8, off offset:128 sc0 sc1\n\t"
        "global_load_dwordx4 %3, %8, off offset:192 sc0 sc1\n\t"
        "global_load_dwordx4 %4, %8, off offset:256 sc0 sc1\n\t"
        "global_load_dwordx4 %5, %8, off offset:320 sc0 sc1\n\t"
        "global_load_dwordx4 %6, %8, off offset:384 sc0 sc1\n\t"
        "global_load_dwordx4 %7, %8, off offset:448 sc0 sc1\n\t"
        "s_waitcnt vmcnt(0)"
        : "=&v"(hq0), "=&v"(hq1), "=&v"(hq2), "=&v"(hq3),
          "=&v"(hq4), "=&v"(hq5), "=&v"(hq6), "=&v"(hq7)
        : "v"(hb)
        : "memory");
      union { uint4 u; short8 s; } cv;
      uint4 hq[8] = { hq0, hq1, hq2, hq3, hq4, hq5, hq6, hq7 };
#pragma unroll
      for (int ks = 0; ks < 8; ++ks) {
        cv.u = hq[ks];
#pragma unroll
        for (int g = 0; g < 4; ++g)
          acc[g] = __builtin_amdgcn_mfma_f32_16x16x32_bf16(cv.s, Bfr[g][ks], acc[g], 0, 0, 0);
      }
    }

    // ---- cross-octant reduction (C/D layout: col = lane&15, row = quad*4+reg)
#pragma unroll
    for (int g = 0; g < 4; ++g)
#pragma unroll
      for (int r = 0; r < 4; ++r)
        atomicAdd(&parts[t & 1][g][quad * 4 + r][nl], acc[g][r]);
    __syncthreads();   // the ONLY barrier per step: parts complete

    // ---- elementwise LSTM update + coherent H store (waves 0-3 == tid<256)
    if (tid < 256) {
      float gI = parts[t & 1][0][eb][eh]; parts[t & 1][0][eb][eh] = 0.f;
      float gF = parts[t & 1][1][eb][eh]; parts[t & 1][1][eb][eh] = 0.f;
      float gO = parts[t & 1][2][eb][eh]; parts[t & 1][2][eb][eh] = 0.f;
      float gC = parts[t & 1][3][eb][eh]; parts[t & 1][3][eb][eh] = 0.f;
      float ig = 1.f / (1.f + __expf(-gI));
      float fg = 1.f / (1.f + __expf(-gF));
      float og = 1.f / (1.f + __expf(-gO));
      float cb = 1.f - 2.f / (__expf(2.f * gC) + 1.f);   // tanh, inf-safe
      c_state = fg * c_state + ig * cb;
      float hn = og * (1.f - 2.f / (__expf(2.f * c_state) + 1.f));
      unsigned short hb = f2bf(hn);
      unsigned short* ps = Hnext + (size_t)(b0 + eb) * HDIM + h0 + eh;
      asm volatile("global_store_short %0, %1, off sc0 sc1"
                   :: "v"(ps), "v"((unsigned)hb) : "memory");
      out[((size_t)t * BATCH + b0 + eb) * HDIM + h0 + eh] = hn;
    }
    // ---- per-wave drain + arrival increment (replaces barrier D + single poller)
    if (w < 4) {
      asm volatile("s_waitcnt vmcnt(0)" ::: "memory");
      if (lane == 0)
        __hip_atomic_fetch_add(mycnt, 1u, __ATOMIC_RELAXED, __HIP_MEMORY_SCOPE_AGENT);
    }
  }
}

extern "C" void kernel_launch(void* const* d_in, const int* in_sizes, int n_in,
                              void* d_out, int out_size, void* d_ws, size_t ws_size,
                              hipStream_t stream) {
  const float* X    = (const float*)d_in[0];
  const float* Wx   = (const float*)d_in[1];
  const float* Wh   = (const float*)d_in[2];
  const float* bias = (const float*)d_in[3];
  const float* mx   = (const float*)d_in[4];
  const float* mh   = (const float*)d_in[5];
  const float* H0   = (const float*)d_in[6];
  const float* C0   = (const float*)d_in[7];
  float* out = (float*)d_out;

  unsigned short* Wcat  = (unsigned short*)d_ws;                       // 16 MB
  unsigned short* Hbuf0 = Wcat + (size_t)4 * HDIM * KDIM;
  unsigned short* Hbuf1 = Hbuf0 + BATCH * HDIM;
  unsigned*       cnt   = (unsigned*)(Hbuf1 + BATCH * HDIM);           // 2 KB

  {
    int tot = 4 * HDIM * KDIM / 4;
    prep_weights<<<(tot + 255) / 256, 256, 0, stream>>>(Wx, Wh, mx, mh, Wcat);
  }
  prep_h0<<<(BATCH * HDIM + 255) / 256, 256, 0, stream>>>(H0, Hbuf0, cnt);

  void* args[] = { (void*)&X, (void*)&bias, (void*)&C0, (void*)&Wcat,
                   (void*)&Hbuf0, (void*)&Hbuf1, (void*)&cnt, (void*)&out };
  hipLaunchCooperativeKernel(reinterpret_cast<void*>(lstm_main),
                             dim3(NWG), dim3(NTHR), args, 0, stream);
}

// Round 7
// 3782.510 us; speedup vs baseline: 1.1906x; 1.1906x over previous
//
#include <hip/hip_runtime.h>

typedef __attribute__((ext_vector_type(8))) short short8;
typedef __attribute__((ext_vector_type(4))) float floatx4;

#define T_STEPS 256
#define BATCH   64
#define IDIM    1024
#define HDIM    1024
#define KDIM    (IDIM + HDIM)   // fused [X | H] K dimension
#define MB      16              // batch rows per WG
#define HB      16              // hidden cols per WG (per gate)
#define NWG     256             // 4 batch-groups x 64 h-groups
#define NTHR    512             // 8 waves = 8 K-octants (0-3 = X, 4-7 = H)
#define QLINES  2               // counter lines per (bg, h-quarter)
#define HPAD    264             // Hsh row stride in elems (256 + 8: 2-way-free banks)

__device__ __forceinline__ unsigned short f2bf(float f) {
  unsigned u = __float_as_uint(f);
  u += 0x7FFFu + ((u >> 16) & 1u);   // round-to-nearest-even
  return (unsigned short)(u >> 16);
}

// Wcat[g][h][k] bf16, k<1024 -> Wx*mx, k>=1024 -> Wh*mh
__global__ void prep_weights(const float* __restrict__ Wx, const float* __restrict__ Wh,
                             const float* __restrict__ mx, const float* __restrict__ mh,
                             unsigned short* __restrict__ Wcat) {
  int idx = blockIdx.x * blockDim.x + threadIdx.x;
  const int total = 4 * HDIM * KDIM / 4;
  if (idx >= total) return;
  int k4 = idx & (KDIM / 4 - 1);
  int gh = idx >> 9;
  int k = k4 * 4;
  float4 v, m;
  if (k < IDIM) {
    v = *(const float4*)(Wx + (size_t)gh * IDIM + k);
    m = *(const float4*)(mx + (size_t)gh * IDIM + k);
  } else {
    v = *(const float4*)(Wh + (size_t)gh * HDIM + (k - IDIM));
    m = *(const float4*)(mh + (size_t)gh * HDIM + (k - IDIM));
  }
  ushort4 o;
  o.x = f2bf(v.x * m.x); o.y = f2bf(v.y * m.y);
  o.z = f2bf(v.z * m.z); o.w = f2bf(v.w * m.w);
  *(ushort4*)(Wcat + (size_t)gh * KDIM + k) = o;
}

// init H0 (bf16) + zero arrival counters
__global__ void prep_h0(const float* __restrict__ H0, unsigned short* __restrict__ Hbuf0,
                        unsigned* __restrict__ cnt) {
  int i = blockIdx.x * blockDim.x + threadIdx.x;
  if (i < BATCH * HDIM) Hbuf0[i] = f2bf(H0[i]);
  if (i < 4 * 4 * QLINES * 16) cnt[i] = 0u;   // [bg][quarter][QLINES] x 16-dword lines
}

__global__ void __launch_bounds__(NTHR, 2)
lstm_main(const float* __restrict__ X,            // [T][B][I] f32
          const float* __restrict__ bias,          // [4][H] f32
          const float* __restrict__ C0,            // [B][H] f32
          const unsigned short* __restrict__ Wcat, // [4][H][K] bf16
          unsigned short* __restrict__ Hbuf0,      // [B][H] bf16 double buffer
          unsigned short* __restrict__ Hbuf1,
          unsigned* __restrict__ cnt,              // [4 bg][4 q][QLINES] x 16-dword lines
          float* __restrict__ out)                 // [T][B][H] f32
{
  __shared__ float parts[2][4][MB][HB + 1];              // 8704 B, dbuf, reset-on-read
  __shared__ __align__(16) unsigned short Hsh[4][MB][HPAD];  // 4 x 8448 B per-wave scratch

  const int tid  = threadIdx.x;
  const int wg   = blockIdx.x;
  const int bg   = wg >> 6;
  const int hg   = wg & 63;
  const int b0   = bg * MB;
  const int h0   = hg * HB;

  const int w    = tid >> 6;       // wave = K-octant 0..7 (0-3 = X, 4-7 = H)
  const int lane = tid & 63;
  const int nl   = lane & 15;
  const int quad = lane >> 4;

  // ---- persistent B fragments: Bfr[g][ks] covers k = w*256 + ks*32 + quad*8 .. +8
  short8 Bfr[4][8];
  {
    const short8* wp = (const short8*)Wcat;
#pragma unroll
    for (int g = 0; g < 4; ++g) {
      const int rowbase = (g * HDIM + h0 + nl) * (KDIM / 8);
#pragma unroll
      for (int ks = 0; ks < 8; ++ks)
        Bfr[g][ks] = wp[rowbase + w * 32 + ks * 4 + quad];
    }
  }

  // ---- zero both parts buffers
  for (int i = tid; i < 2 * 4 * MB * (HB + 1); i += NTHR)
    (&parts[0][0][0][0])[i] = 0.f;

  // ---- per-thread cell state (threads 0..255 own a (b,h) cell)
  float c_state = 0.f;
  const int eb = tid >> 4;
  const int eh = tid & 15;
  if (tid < 256) c_state = C0[(b0 + eb) * HDIM + h0 + eh];

  // ---- bias slice (only wave 0 folds it into its accumulator)
  float sb[4];
#pragma unroll
  for (int g = 0; g < 4; ++g) sb[g] = bias[g * HDIM + h0 + nl];

  // producer: signal line of this WG's h-quarter; consumer wave w: lines of quarter w-4
  unsigned* mycnt = cnt + ((bg * 4 + (hg >> 4)) * QLINES + (hg & 1)) * 16;
  unsigned* qbase = cnt + ((bg * 4 + (w & 3)) * QLINES) * 16;   // valid when w>=4

  // ---- X prefetch for t=0 (X-waves only; fragment-layout registers)
  uint4 Xpre[16];
  if (w < 4) {
    const uint4* u = (const uint4*)(X + ((size_t)0 * BATCH + b0 + nl) * IDIM
                                      + w * 256 + quad * 8);
#pragma unroll
    for (int ks = 0; ks < 8; ++ks) {
      Xpre[2 * ks]     = u[ks * 8];
      Xpre[2 * ks + 1] = u[ks * 8 + 1];
    }
  }

  __syncthreads();   // parts zero-init visible

  for (int t = 0; t < T_STEPS; ++t) {
    const unsigned short* __restrict__ Hprev = (t & 1) ? Hbuf1 : Hbuf0;
    unsigned short* __restrict__ Hnext       = (t & 1) ? Hbuf0 : Hbuf1;

    floatx4 acc[4];
#pragma unroll
    for (int g = 0; g < 4; ++g) acc[g] = floatx4{0.f, 0.f, 0.f, 0.f};

    if (w < 4) {
      // ---- X octant: MFMA straight from prefetched registers, never waits
#pragma unroll
      for (int ks = 0; ks < 8; ++ks) {
        uint4 lo = Xpre[2 * ks], hi = Xpre[2 * ks + 1];
        short8 af;
        af[0] = (short)f2bf(__uint_as_float(lo.x));
        af[1] = (short)f2bf(__uint_as_float(lo.y));
        af[2] = (short)f2bf(__uint_as_float(lo.z));
        af[3] = (short)f2bf(__uint_as_float(lo.w));
        af[4] = (short)f2bf(__uint_as_float(hi.x));
        af[5] = (short)f2bf(__uint_as_float(hi.y));
        af[6] = (short)f2bf(__uint_as_float(hi.z));
        af[7] = (short)f2bf(__uint_as_float(hi.w));
#pragma unroll
        for (int g = 0; g < 4; ++g)
          acc[g] = __builtin_amdgcn_mfma_f32_16x16x32_bf16(af, Bfr[g][ks], acc[g], 0, 0, 0);
      }
      if (w == 0) {
#pragma unroll
        for (int g = 0; g < 4; ++g)
#pragma unroll
          for (int r = 0; r < 4; ++r)
            acc[g][r] += sb[g];
      }
      // parts contribution now, then prefetch X for t+1 (hidden in barrier slack)
#pragma unroll
      for (int g = 0; g < 4; ++g)
#pragma unroll
        for (int r = 0; r < 4; ++r)
          atomicAdd(&parts[t & 1][g][quad * 4 + r][nl], acc[g][r]);
      {
        int tn = (t + 1 < T_STEPS) ? t + 1 : t;
        const uint4* u = (const uint4*)(X + ((size_t)tn * BATCH + b0 + nl) * IDIM
                                          + w * 256 + quad * 8);
#pragma unroll
        for (int ks = 0; ks < 8; ++ks) {
          Xpre[2 * ks]     = u[ks * 8];
          Xpre[2 * ks + 1] = u[ks * 8 + 1];
        }
      }
    } else {
      // ---- H octant: lane-0 poll blocks the whole wave (no broadcast needed)
      if (t > 0 && lane == 0) {
        const unsigned tgt = 64u * (unsigned)t;   // 16 WGs x 4 waves per quarter-step
        for (;;) {
          unsigned s = __hip_atomic_load(qbase,      __ATOMIC_RELAXED, __HIP_MEMORY_SCOPE_AGENT)
                     + __hip_atomic_load(qbase + 16, __ATOMIC_RELAXED, __HIP_MEMORY_SCOPE_AGENT);
          if (s >= tgt) break;
          __builtin_amdgcn_s_sleep(8);
        }
      }
      // coalesced coherent load of this wave's own K-quarter (rows 0-15 x 256 cols)
      // lane covers rows {2i + (lane>>5)}, col chunk (lane&31)*8 .. +8
      const int rhi = lane >> 5, c16 = lane & 31;
      const unsigned short* p0 = Hprev + (size_t)(b0 + rhi) * HDIM + (w - 4) * 256 + c16 * 8;
      uint4 d0, d1, d2, d3, d4, d5, d6, d7;
      asm volatile(
        "global_load_dwordx4 %0, %8, off sc0 sc1\n\t"
        "global_load_dwordx4 %1, %9, off sc0 sc1\n\t"
        "global_load_dwordx4 %2, %10, off sc0 sc1\n\t"
        "global_load_dwordx4 %3, %11, off sc0 sc1\n\t"
        "global_load_dwordx4 %4, %12, off sc0 sc1\n\t"
        "global_load_dwordx4 %5, %13, off sc0 sc1\n\t"
        "global_load_dwordx4 %6, %14, off sc0 sc1\n\t"
        "global_load_dwordx4 %7, %15, off sc0 sc1\n\t"
        "s_waitcnt vmcnt(0)"
        : "=&v"(d0), "=&v"(d1), "=&v"(d2), "=&v"(d3),
          "=&v"(d4), "=&v"(d5), "=&v"(d6), "=&v"(d7)
        : "v"(p0),             "v"(p0 +  2 * HDIM), "v"(p0 +  4 * HDIM), "v"(p0 +  6 * HDIM),
          "v"(p0 +  8 * HDIM), "v"(p0 + 10 * HDIM), "v"(p0 + 12 * HDIM), "v"(p0 + 14 * HDIM)
        : "memory");
      // bounce through per-wave LDS scratch (no cross-wave deps, no barrier)
      unsigned short* hs = &Hsh[w - 4][0][0];
      *(uint4*)&hs[(rhi +  0) * HPAD + c16 * 8] = d0;
      *(uint4*)&hs[(rhi +  2) * HPAD + c16 * 8] = d1;
      *(uint4*)&hs[(rhi +  4) * HPAD + c16 * 8] = d2;
      *(uint4*)&hs[(rhi +  6) * HPAD + c16 * 8] = d3;
      *(uint4*)&hs[(rhi +  8) * HPAD + c16 * 8] = d4;
      *(uint4*)&hs[(rhi + 10) * HPAD + c16 * 8] = d5;
      *(uint4*)&hs[(rhi + 12) * HPAD + c16 * 8] = d6;
      *(uint4*)&hs[(rhi + 14) * HPAD + c16 * 8] = d7;
      asm volatile("s_waitcnt lgkmcnt(0)" ::: "memory");
      __builtin_amdgcn_sched_barrier(0);
      // fragment reads + MFMA
#pragma unroll
      for (int ks = 0; ks < 8; ++ks) {
        short8 af = *(const short8*)&hs[nl * HPAD + quad * 8 + ks * 32];
#pragma unroll
        for (int g = 0; g < 4; ++g)
          acc[g] = __builtin_amdgcn_mfma_f32_16x16x32_bf16(af, Bfr[g][ks], acc[g], 0, 0, 0);
      }
#pragma unroll
      for (int g = 0; g < 4; ++g)
#pragma unroll
        for (int r = 0; r < 4; ++r)
          atomicAdd(&parts[t & 1][g][quad * 4 + r][nl], acc[g][r]);
    }

    __syncthreads();   // the ONLY barrier per step: parts complete

    // ---- elementwise LSTM update + coherent H store (waves 0-3 == tid<256)
    if (tid < 256) {
      float gI = parts[t & 1][0][eb][eh]; parts[t & 1][0][eb][eh] = 0.f;
      float gF = parts[t & 1][1][eb][eh]; parts[t & 1][1][eb][eh] = 0.f;
      float gO = parts[t & 1][2][eb][eh]; parts[t & 1][2][eb][eh] = 0.f;
      float gC = parts[t & 1][3][eb][eh]; parts[t & 1][3][eb][eh] = 0.f;
      float ig = 1.f / (1.f + __expf(-gI));
      float fg = 1.f / (1.f + __expf(-gF));
      float og = 1.f / (1.f + __expf(-gO));
      float cb = 1.f - 2.f / (__expf(2.f * gC) + 1.f);   // tanh, inf-safe
      c_state = fg * c_state + ig * cb;
      float hn = og * (1.f - 2.f / (__expf(2.f * c_state) + 1.f));
      unsigned short hbf = f2bf(hn);
      unsigned short* ps = Hnext + (size_t)(b0 + eb) * HDIM + h0 + eh;
      asm volatile("global_store_short %0, %1, off sc0 sc1"
                   :: "v"(ps), "v"((unsigned)hbf) : "memory");
      out[((size_t)t * BATCH + b0 + eb) * HDIM + h0 + eh] = hn;
    }
    // ---- per-wave drain + one arrival increment per producer wave
    if (w < 4) {
      asm volatile("s_waitcnt vmcnt(0)" ::: "memory");
      if (lane == 0)
        __hip_atomic_fetch_add(mycnt, 1u, __ATOMIC_RELAXED, __HIP_MEMORY_SCOPE_AGENT);
    }
  }
}

extern "C" void kernel_launch(void* const* d_in, const int* in_sizes, int n_in,
                              void* d_out, int out_size, void* d_ws, size_t ws_size,
                              hipStream_t stream) {
  const float* X    = (const float*)d_in[0];
  const float* Wx   = (const float*)d_in[1];
  const float* Wh   = (const float*)d_in[2];
  const float* bias = (const float*)d_in[3];
  const float* mx   = (const float*)d_in[4];
  const float* mh   = (const float*)d_in[5];
  const float* H0   = (const float*)d_in[6];
  const float* C0   = (const float*)d_in[7];
  float* out = (float*)d_out;

  unsigned short* Wcat  = (unsigned short*)d_ws;                       // 16 MB
  unsigned short* Hbuf0 = Wcat + (size_t)4 * HDIM * KDIM;
  unsigned short* Hbuf1 = Hbuf0 + BATCH * HDIM;
  unsigned*       cnt   = (unsigned*)(Hbuf1 + BATCH * HDIM);           // 2 KB

  {
    int tot = 4 * HDIM * KDIM / 4;
    prep_weights<<<(tot + 255) / 256, 256, 0, stream>>>(Wx, Wh, mx, mh, Wcat);
  }
  prep_h0<<<(BATCH * HDIM + 255) / 256, 256, 0, stream>>>(H0, Hbuf0, cnt);

  void* args[] = { (void*)&X, (void*)&bias, (void*)&C0, (void*)&Wcat,
                   (void*)&Hbuf0, (void*)&Hbuf1, (void*)&cnt, (void*)&out };
  hipLaunchCooperativeKernel(reinterpret_cast<void*>(lstm_main),
                             dim3(NWG), dim3(NTHR), args, 0, stream);
}